// Round 1
// baseline (682.782 us; speedup 1.0000x reference)
//
#include <hip/hip_runtime.h>
#include <hip/hip_bf16.h>

typedef _Float16 half8 __attribute__((ext_vector_type(8)));
typedef _Float16 half4v __attribute__((ext_vector_type(4)));
typedef float f32x4 __attribute__((ext_vector_type(4)));

#define DEV static __device__ __forceinline__

// Problem constants: B=4, T=1024, D=1024, H=16, HD=64, TP=1024, SKV=2048

// ---------------------------------------------------------------------------
// Weight prep: w = tanh(wt)*sigmoid(mt), stored TRANSPOSED (N x K=1024) as f16
// so GEMM B-operand fragments are K-contiguous.
// grid = (N/64)*(K/64), 256 threads
__global__ __launch_bounds__(256) void prep_w(const float* __restrict__ wt,
                                              const float* __restrict__ mt,
                                              _Float16* __restrict__ out, int N) {
  __shared__ float tile[64][65];
  const int ntiles = N >> 6;
  const int nt = blockIdx.x % ntiles, kt = blockIdx.x / ntiles;
  const int k0 = kt << 6, n0 = nt << 6;
  const int t = threadIdx.x, r = t >> 2, c0 = (t & 3) << 4;
  const long ibase = (long)(k0 + r) * N + n0 + c0;
#pragma unroll
  for (int j = 0; j < 16; j += 4) {
    float4 a = *(const float4*)(wt + ibase + j);
    float4 b = *(const float4*)(mt + ibase + j);
    tile[r][c0 + j + 0] = tanhf(a.x) / (1.f + __expf(-b.x));
    tile[r][c0 + j + 1] = tanhf(a.y) / (1.f + __expf(-b.y));
    tile[r][c0 + j + 2] = tanhf(a.z) / (1.f + __expf(-b.z));
    tile[r][c0 + j + 3] = tanhf(a.w) / (1.f + __expf(-b.w));
  }
  __syncthreads();
  half8 o0, o1;
#pragma unroll
  for (int j = 0; j < 8; ++j) {
    o0[j] = (_Float16)tile[c0 + j][r];
    o1[j] = (_Float16)tile[c0 + 8 + j][r];
  }
  _Float16* dst = out + (long)(n0 + r) * 1024 + k0 + c0;
  *(half8*)dst = o0;
  *(half8*)(dst + 8) = o1;
}

// ---------------------------------------------------------------------------
// past[:,0] (k) fp32 -> k_full rows 0..1023 f16.  grid 4096 x 256, 4 elems/thr
__global__ __launch_bounds__(256) void conv_pastk(const float* __restrict__ past,
                                                  _Float16* __restrict__ kf) {
  const long e = ((long)blockIdx.x * 256 + threadIdx.x) * 4;
  const int b = (int)(e >> 20);
  const int rem = (int)(e & 1048575);        // h*65536 + t*64 + d
  const int h = rem >> 16;
  const int td = rem & 65535;
  float4 v = *(const float4*)(past + (long)b * 2097152 + rem);
  half4v o = {(_Float16)v.x, (_Float16)v.y, (_Float16)v.z, (_Float16)v.w};
  *(half4v*)(kf + (long)(b * 16 + h) * 131072 + td) = o;   // 2048*64 = 131072
}

// ---------------------------------------------------------------------------
// LayerNorm row kernel: fp32 in -> f16 out. grid 4096 rows x 256 threads.
__global__ __launch_bounds__(256) void ln_k(const float* __restrict__ x,
                                            const float* __restrict__ g,
                                            const float* __restrict__ be,
                                            _Float16* __restrict__ out) {
  __shared__ float red[4];
  const int row = blockIdx.x, tid = threadIdx.x, l = tid & 63, w = tid >> 6;
  float4 v = *(const float4*)(x + (long)row * 1024 + tid * 4);
  float s = v.x + v.y + v.z + v.w;
#pragma unroll
  for (int o = 32; o > 0; o >>= 1) s += __shfl_down(s, o, 64);
  if (l == 0) red[w] = s;
  __syncthreads();
  const float mu = (red[0] + red[1] + red[2] + red[3]) * (1.f / 1024.f);
  float dx = v.x - mu, dy = v.y - mu, dz = v.z - mu, dw = v.w - mu;
  float ss = dx * dx + dy * dy + dz * dz + dw * dw;
#pragma unroll
  for (int o = 32; o > 0; o >>= 1) ss += __shfl_down(ss, o, 64);
  __syncthreads();
  if (l == 0) red[w] = ss;
  __syncthreads();
  const float var = (red[0] + red[1] + red[2] + red[3]) * (1.f / 1024.f);
  const float rs = rsqrtf(var + 1e-3f);
  float4 gv = *(const float4*)(g + tid * 4);
  float4 bv = *(const float4*)(be + tid * 4);
  half4v o = {(_Float16)(dx * rs * gv.x + bv.x), (_Float16)(dy * rs * gv.y + bv.y),
              (_Float16)(dz * rs * gv.z + bv.z), (_Float16)(dw * rs * gv.w + bv.w)};
  *(half4v*)(out + (long)row * 1024 + tid * 4) = o;
}

// ---------------------------------------------------------------------------
// GEMM 128x128 tile, BK=64, 256 threads (4 waves, 2x2), K=1024 fixed.
// A (MxK) f16 row-major, Bt (NxK) f16 row-major. XOR-swizzled LDS.
// EPI 0: QKV scatter epilogue. EPI 1: out = res + acc.
template <int EPI>
__global__ __launch_bounds__(256) void gemm128(const _Float16* __restrict__ A,
                                               const _Float16* __restrict__ Bt,
                                               int mtiles,
                                               _Float16* __restrict__ e_q,
                                               _Float16* __restrict__ e_k,
                                               _Float16* __restrict__ e_v,
                                               float* __restrict__ e_present,
                                               const float* __restrict__ e_res,
                                               float* __restrict__ e_out) {
  __shared__ __align__(16) char smem[32768];
  char* As = smem;
  char* Bs = smem + 16384;
  const int tid = threadIdx.x, l = tid & 63, w = tid >> 6;
  const int wm = w >> 1, wn = w & 1;
  const int bm = blockIdx.x % mtiles, bn = blockIdx.x / mtiles;
  const long m0 = (long)bm << 7, n0 = (long)bn << 7;

  const f32x4 zf = {0.f, 0.f, 0.f, 0.f};
  f32x4 acc[4][4];
#pragma unroll
  for (int i = 0; i < 4; ++i) {
#pragma unroll
    for (int j = 0; j < 4; ++j) acc[i][j] = zf;
  }

  float4 ra[4], rb[4];
#pragma unroll
  for (int i = 0; i < 4; ++i) {
    int cid = i * 256 + tid, row = cid >> 3, slot = cid & 7;
    ra[i] = *(const float4*)(A + (m0 + row) * 1024 + slot * 8);
    rb[i] = *(const float4*)(Bt + (n0 + row) * 1024 + slot * 8);
  }
  for (int kt = 0; kt < 16; ++kt) {
    __syncthreads();
#pragma unroll
    for (int i = 0; i < 4; ++i) {
      int cid = i * 256 + tid, row = cid >> 3, slot = cid & 7;
      int sb = row * 128 + ((slot ^ (row & 7)) << 4);
      *(float4*)(As + sb) = ra[i];
      *(float4*)(Bs + sb) = rb[i];
    }
    __syncthreads();
    if (kt + 1 < 16) {
#pragma unroll
      for (int i = 0; i < 4; ++i) {
        int cid = i * 256 + tid, row = cid >> 3, slot = cid & 7;
        ra[i] = *(const float4*)(A + (m0 + row) * 1024 + (kt + 1) * 64 + slot * 8);
        rb[i] = *(const float4*)(Bt + (n0 + row) * 1024 + (kt + 1) * 64 + slot * 8);
      }
    }
#pragma unroll
    for (int k2 = 0; k2 < 2; ++k2) {
      const int sl = k2 * 4 + (l >> 4);
      half8 bfr[4];
#pragma unroll
      for (int fn = 0; fn < 4; ++fn) {
        const int rn = wn * 64 + fn * 16 + (l & 15);
        bfr[fn] = *(const half8*)(Bs + rn * 128 + ((sl ^ (rn & 7)) << 4));
      }
#pragma unroll
      for (int fm = 0; fm < 4; ++fm) {
        const int rm = wm * 64 + fm * 16 + (l & 15);
        const half8 afr = *(const half8*)(As + rm * 128 + ((sl ^ (rm & 7)) << 4));
#pragma unroll
        for (int fn = 0; fn < 4; ++fn)
          acc[fm][fn] = __builtin_amdgcn_mfma_f32_16x16x32_f16(afr, bfr[fn], acc[fm][fn], 0, 0, 0);
      }
    }
  }
  // epilogue: C/D layout col = l&15, row = (l>>4)*4 + r
#pragma unroll
  for (int fm = 0; fm < 4; ++fm) {
#pragma unroll
    for (int fn = 0; fn < 4; ++fn) {
#pragma unroll
      for (int r = 0; r < 4; ++r) {
        const long row = m0 + wm * 64 + fm * 16 + (l >> 4) * 4 + r;
        const long col = n0 + wn * 64 + fn * 16 + (l & 15);
        const float v = acc[fm][fn][r];
        if constexpr (EPI == 0) {
          const int b = (int)(row >> 10), t = (int)(row & 1023);
          const int sec = (int)(col >> 10), h = ((int)col >> 6) & 15, hd = (int)col & 63;
          const long bh = b * 16 + h;
          if (sec == 0) {
            e_q[(bh * 1024 + t) * 64 + hd] = (_Float16)v;
          } else if (sec == 1) {
            e_present[(((long)(b * 2) * 16 + h) * 1024 + t) * 64 + hd] = v;
            e_k[(bh * 2048 + 1024 + t) * 64 + hd] = (_Float16)v;
          } else {
            e_present[(((long)(b * 2 + 1) * 16 + h) * 1024 + t) * 64 + hd] = v;
            e_v[(bh * 1024 + t) * 64 + hd] = (_Float16)v;
          }
        } else {
          e_out[row * 1024 + col] = e_res[row * 1024 + col] + v;
        }
      }
    }
  }
}

// ---------------------------------------------------------------------------
// Build v^T (B,H,64,2048) f16 from past v (fp32) + new v (f16).
// grid = B*H*32 (k-tiles of 64), 256 threads, LDS 64x65 transpose.
__global__ __launch_bounds__(256) void vt_transpose(const float* __restrict__ past,
                                                    const _Float16* __restrict__ vnew,
                                                    _Float16* __restrict__ vt) {
  __shared__ float tile[64][65];
  const int bh = blockIdx.x >> 5, kt = blockIdx.x & 31;
  const int b = bh >> 4, h = bh & 15;
  const int k0 = kt << 6;
  const int t = threadIdx.x, r = t >> 2, c0 = (t & 3) << 4;
  if (k0 < 1024) {
    const float* src = past + (((long)(b * 2 + 1) * 16 + h) * 1024 + (k0 + r)) * 64 + c0;
#pragma unroll
    for (int j = 0; j < 16; j += 4) {
      float4 v = *(const float4*)(src + j);
      tile[r][c0 + j + 0] = v.x;
      tile[r][c0 + j + 1] = v.y;
      tile[r][c0 + j + 2] = v.z;
      tile[r][c0 + j + 3] = v.w;
    }
  } else {
    const _Float16* src = vnew + ((long)bh * 1024 + (k0 - 1024 + r)) * 64 + c0;
    half8 a = *(const half8*)src;
    half8 bq = *(const half8*)(src + 8);
#pragma unroll
    for (int j = 0; j < 8; ++j) {
      tile[r][c0 + j] = (float)a[j];
      tile[r][c0 + 8 + j] = (float)bq[j];
    }
  }
  __syncthreads();
  half8 o0, o1;
#pragma unroll
  for (int j = 0; j < 8; ++j) {
    o0[j] = (_Float16)tile[c0 + j][r];
    o1[j] = (_Float16)tile[c0 + 8 + j][r];
  }
  _Float16* dst = vt + ((long)bh * 64 + r) * 2048 + k0 + c0;
  *(half8*)dst = o0;
  *(half8*)(dst + 8) = o1;
}

// ---------------------------------------------------------------------------
// Fused attention. One block per (b,h,q-tile-of-128). 256 threads.
// Phase 1: online row max/sumexp over kv chunks of 128 (S = q k^T, 2x2 waves).
// Phase 2: recompute S, P = exp(S-m)/l, write msk fp32, P->LDS f16, PV MFMA.
DEV void s_mfma_tile(const char* qs, const char* ks, int l, int wm, int wn,
                     f32x4 (&sa)[4][4]) {
  const f32x4 zf = {0.f, 0.f, 0.f, 0.f};
#pragma unroll
  for (int i = 0; i < 4; ++i) {
#pragma unroll
    for (int j = 0; j < 4; ++j) sa[i][j] = zf;
  }
#pragma unroll
  for (int k2 = 0; k2 < 2; ++k2) {
    const int sl = k2 * 4 + (l >> 4);
    half8 bfr[4];
#pragma unroll
    for (int fn = 0; fn < 4; ++fn) {
      const int rn = wn * 64 + fn * 16 + (l & 15);
      bfr[fn] = *(const half8*)(ks + rn * 128 + ((sl ^ (rn & 7)) << 4));
    }
#pragma unroll
    for (int fm = 0; fm < 4; ++fm) {
      const int rm = wm * 64 + fm * 16 + (l & 15);
      const half8 afr = *(const half8*)(qs + rm * 128 + ((sl ^ (rm & 7)) << 4));
#pragma unroll
      for (int fn = 0; fn < 4; ++fn)
        sa[fm][fn] = __builtin_amdgcn_mfma_f32_16x16x32_f16(afr, bfr[fn], sa[fm][fn], 0, 0, 0);
    }
  }
}

__global__ __launch_bounds__(256) void attn_k(const _Float16* __restrict__ qg,
                                              const _Float16* __restrict__ kg,
                                              const _Float16* __restrict__ vtg,
                                              float* __restrict__ msk,
                                              _Float16* __restrict__ ah) {
  __shared__ __align__(16) char smem[68608];
  char* qs = smem;                       // [128][128B] swizzled (q tile)
  char* ks = smem + 16384;               // [128][128B] k chunk; aliased as vts [64][256B]
  char* ps = smem + 32768;               // [128][256B] P chunk f16
  float* mrow = (float*)(smem + 65536);  // [128]
  float* lrow = (float*)(smem + 66048);  // [128]
  float* mtmp = (float*)(smem + 66560);  // [2][128]
  float* stmp = (float*)(smem + 67584);  // [2][128]

  const int tid = threadIdx.x, l = tid & 63, w = tid >> 6;
  const int wm = w >> 1, wn = w & 1;
  const int bh = blockIdx.x >> 3, qt = blockIdx.x & 7;
  const int r0 = qt << 7;
  const int nc = qt + 9;  // kv chunks needed (cols <= r0+127+1024)

  const _Float16* qbase = qg + ((long)bh * 1024 + r0) * 64;
  const _Float16* kbase = kg + (long)bh * 131072;
  const _Float16* vtbase = vtg + (long)bh * 131072;
  float* mskbase = msk + ((long)bh * 1024 + r0) * 2048;

  // stage q (persists all kernel)
#pragma unroll
  for (int i = 0; i < 4; ++i) {
    int cid = i * 256 + tid, row = cid >> 3, slot = cid & 7;
    float4 rv = *(const float4*)(qbase + row * 64 + slot * 8);
    *(float4*)(qs + row * 128 + ((slot ^ (row & 7)) << 4)) = rv;
  }

  // ---- phase 1
  float m_t[16], s_t[16];
#pragma unroll
  for (int i = 0; i < 16; ++i) {
    m_t[i] = -1e30f;
    s_t[i] = 0.f;
  }
  for (int c = 0; c < nc; ++c) {
    float4 rk[4];
#pragma unroll
    for (int i = 0; i < 4; ++i) {
      int cid = i * 256 + tid, row = cid >> 3, slot = cid & 7;
      rk[i] = *(const float4*)(kbase + (long)(c * 128 + row) * 64 + slot * 8);
    }
    __syncthreads();
#pragma unroll
    for (int i = 0; i < 4; ++i) {
      int cid = i * 256 + tid, row = cid >> 3, slot = cid & 7;
      *(float4*)(ks + row * 128 + ((slot ^ (row & 7)) << 4)) = rk[i];
    }
    __syncthreads();
    f32x4 sa[4][4];
    s_mfma_tile(qs, ks, l, wm, wn, sa);
#pragma unroll
    for (int fm = 0; fm < 4; ++fm) {
#pragma unroll
      for (int r = 0; r < 4; ++r) {
        const int row_l = wm * 64 + fm * 16 + (l >> 4) * 4 + r;
        const int lim = r0 + row_l + 1024;  // allowed: col <= lim
        float vv[4];
#pragma unroll
        for (int fn = 0; fn < 4; ++fn) {
          const int col = c * 128 + wn * 64 + fn * 16 + (l & 15);
          vv[fn] = (col <= lim) ? sa[fm][fn][r] * 0.125f : -1e30f;
        }
        const float cm = fmaxf(fmaxf(vv[0], vv[1]), fmaxf(vv[2], vv[3]));
        const int ix = fm * 4 + r;
        const float mo = m_t[ix];
        const float mn = fmaxf(mo, cm);
        s_t[ix] = s_t[ix] * __expf(mo - mn) + __expf(vv[0] - mn) + __expf(vv[1] - mn) +
                  __expf(vv[2] - mn) + __expf(vv[3] - mn);
        m_t[ix] = mn;
      }
    }
  }
  // reduce across the 16 lanes sharing a row
#pragma unroll
  for (int ix = 0; ix < 16; ++ix) {
    float m = m_t[ix], s = s_t[ix];
#pragma unroll
    for (int mk = 1; mk <= 8; mk <<= 1) {
      const float om = __shfl_xor(m, mk, 64);
      const float os = __shfl_xor(s, mk, 64);
      const float mn = fmaxf(m, om);
      s = s * __expf(m - mn) + os * __expf(om - mn);
      m = mn;
    }
    m_t[ix] = m;
    s_t[ix] = s;
  }
  if ((l & 15) == 0) {
#pragma unroll
    for (int fm = 0; fm < 4; ++fm) {
#pragma unroll
      for (int r = 0; r < 4; ++r) {
        const int row_l = wm * 64 + fm * 16 + (l >> 4) * 4 + r;
        mtmp[wn * 128 + row_l] = m_t[fm * 4 + r];
        stmp[wn * 128 + row_l] = s_t[fm * 4 + r];
      }
    }
  }
  __syncthreads();
  if (tid < 128) {  // combine the two column-half waves
    const float m0v = mtmp[tid], m1v = mtmp[128 + tid];
    const float s0v = stmp[tid], s1v = stmp[128 + tid];
    const float mn = fmaxf(m0v, m1v);
    mrow[tid] = mn;
    lrow[tid] = 1.f / (s0v * __expf(m0v - mn) + s1v * __expf(m1v - mn));
  }
  __syncthreads();

  // ---- phase 2
  const f32x4 zf = {0.f, 0.f, 0.f, 0.f};
  f32x4 pv[2][4];
#pragma unroll
  for (int i = 0; i < 2; ++i) {
#pragma unroll
    for (int j = 0; j < 4; ++j) pv[i][j] = zf;
  }
  for (int c = 0; c < nc; ++c) {
    float4 rk[4];
#pragma unroll
    for (int i = 0; i < 4; ++i) {
      int cid = i * 256 + tid, row = cid >> 3, slot = cid & 7;
      rk[i] = *(const float4*)(kbase + (long)(c * 128 + row) * 64 + slot * 8);
    }
    __syncthreads();  // prior PV frag reads done
#pragma unroll
    for (int i = 0; i < 4; ++i) {
      int cid = i * 256 + tid, row = cid >> 3, slot = cid & 7;
      *(float4*)(ks + row * 128 + ((slot ^ (row & 7)) << 4)) = rk[i];
    }
    __syncthreads();
    f32x4 sa[4][4];
    s_mfma_tile(qs, ks, l, wm, wn, sa);
    float4 rv4[4];  // issue v^T loads early; latency hides under exp/stores
#pragma unroll
    for (int i = 0; i < 4; ++i) {
      int cid = i * 256 + tid, row = cid >> 4, slot = cid & 15;
      rv4[i] = *(const float4*)(vtbase + (long)row * 2048 + c * 128 + slot * 8);
    }
#pragma unroll
    for (int fm = 0; fm < 4; ++fm) {
#pragma unroll
      for (int r = 0; r < 4; ++r) {
        const int row_l = wm * 64 + fm * 16 + (l >> 4) * 4 + r;
        const int lim = r0 + row_l + 1024;
        const float mref = mrow[row_l], linv = lrow[row_l];
#pragma unroll
        for (int fn = 0; fn < 4; ++fn) {
          const int col_l = wn * 64 + fn * 16 + (l & 15);
          const int col = c * 128 + col_l;
          const float p =
              (col <= lim) ? __expf(sa[fm][fn][r] * 0.125f - mref) * linv : 0.f;
          mskbase[(long)row_l * 2048 + col] = p;
          *(_Float16*)(ps + row_l * 256 + (((col_l >> 3) ^ (row_l & 7)) << 4) +
                       ((col_l & 7) << 1)) = (_Float16)p;
        }
      }
    }
    __syncthreads();  // S frag reads of ks done -> safe to overwrite with vts
#pragma unroll
    for (int i = 0; i < 4; ++i) {
      int cid = i * 256 + tid, row = cid >> 4, slot = cid & 15;
      *(float4*)(ks + row * 256 + ((slot ^ (row & 7)) << 4)) = rv4[i];
    }
    __syncthreads();  // ps + vts visible
#pragma unroll
    for (int k2 = 0; k2 < 4; ++k2) {
      const int sl = k2 * 4 + (l >> 4);
      half8 bv[4];
#pragma unroll
      for (int fn2 = 0; fn2 < 4; ++fn2) {
        const int rd = fn2 * 16 + (l & 15);
        bv[fn2] = *(const half8*)(ks + rd * 256 + ((sl ^ (rd & 7)) << 4));
      }
#pragma unroll
      for (int fm2 = 0; fm2 < 2; ++fm2) {
        const int rp = w * 32 + fm2 * 16 + (l & 15);
        const half8 ap = *(const half8*)(ps + rp * 256 + ((sl ^ (rp & 7)) << 4));
#pragma unroll
        for (int fn2 = 0; fn2 < 4; ++fn2)
          pv[fm2][fn2] = __builtin_amdgcn_mfma_f32_16x16x32_f16(ap, bv[fn2], pv[fm2][fn2], 0, 0, 0);
      }
    }
  }
  // zero-fill fully-masked tail columns of msk
  const int rem4 = (16 - nc) << 5;  // float4s per row
  if (rem4 > 0) {
    const float4 z4 = make_float4(0.f, 0.f, 0.f, 0.f);
    for (int row = 0; row < 128; ++row)
      for (int i = tid; i < rem4; i += 256)
        *(float4*)(mskbase + (long)row * 2048 + nc * 128 + i * 4) = z4;
  }
  // write attention output rows into ah (B*T, 1024) f16 (merge GEMM A operand)
  const int b = bh >> 4, h = bh & 15;
#pragma unroll
  for (int fm2 = 0; fm2 < 2; ++fm2) {
#pragma unroll
    for (int fn2 = 0; fn2 < 4; ++fn2) {
#pragma unroll
      for (int r = 0; r < 4; ++r) {
        const int row_l = w * 32 + fm2 * 16 + (l >> 4) * 4 + r;
        const long bt = (long)b * 1024 + r0 + row_l;
        const int d = fn2 * 16 + (l & 15);
        ah[bt * 1024 + h * 64 + d] = (_Float16)pv[fm2][fn2][r];
      }
    }
  }
}

// ---------------------------------------------------------------------------
extern "C" void kernel_launch(void* const* d_in, const int* in_sizes, int n_in,
                              void* d_out, int out_size, void* d_ws, size_t ws_size,
                              hipStream_t stream) {
  const float* x = (const float*)d_in[0];
  const float* past = (const float*)d_in[1];
  const float* qkv_wt = (const float*)d_in[2];
  const float* qkv_mt = (const float*)d_in[3];
  const float* merge_wt = (const float*)d_in[4];
  const float* merge_mt = (const float*)d_in[5];
  const float* ln1_wt = (const float*)d_in[6];
  const float* ln1_mt = (const float*)d_in[7];
  const float* g1 = (const float*)d_in[8];
  const float* b1 = (const float*)d_in[9];
  const float* g2 = (const float*)d_in[10];
  const float* b2 = (const float*)d_in[11];

  float* out = (float*)d_out;
  float* o_xm = out;                       // (4,1024,1024)
  float* o_present = out + 4194304;        // (4,2,16,1024,64)
  float* o_msk = out + 4194304 + 8388608;  // (4,16,1024,2048)

  char* ws = (char*)d_ws;
  _Float16* wq_t = (_Float16*)(ws + 0);         // 3072x1024 f16  (6 MB)
  _Float16* wm_t = (_Float16*)(ws + 6291456);   // 1024x1024 f16  (2 MB)
  _Float16* wl_t = (_Float16*)(ws + 8388608);   // 1024x1024 f16  (2 MB)
  _Float16* xn   = (_Float16*)(ws + 10485760);  // 4096x1024 f16  (8 MB, reused for LN2)
  _Float16* qws  = (_Float16*)(ws + 18874368);  // (4,16,1024,64) (8 MB)
  _Float16* kful = (_Float16*)(ws + 27262976);  // (4,16,2048,64) (16 MB)
  _Float16* vnew = (_Float16*)(ws + 44040192);  // (4,16,1024,64) (8 MB)
  _Float16* vt   = (_Float16*)(ws + 52428800);  // (4,16,64,2048) (16 MB)
  _Float16* ah   = (_Float16*)(ws + 69206016);  // 4096x1024 f16  (8 MB)
  float* xa      = (float*)(ws + 77594624);     // 4096x1024 f32  (16 MB) -> 94371840 total

  prep_w<<<768, 256, 0, stream>>>(qkv_wt, qkv_mt, wq_t, 3072);
  prep_w<<<256, 256, 0, stream>>>(merge_wt, merge_mt, wm_t, 1024);
  prep_w<<<256, 256, 0, stream>>>(ln1_wt, ln1_mt, wl_t, 1024);
  conv_pastk<<<4096, 256, 0, stream>>>(past, kful);
  ln_k<<<4096, 256, 0, stream>>>(x, g1, b1, xn);
  gemm128<0><<<768, 256, 0, stream>>>(xn, wq_t, 32, qws, kful, vnew, o_present,
                                      nullptr, nullptr);
  vt_transpose<<<2048, 256, 0, stream>>>(past, vnew, vt);
  attn_k<<<512, 256, 0, stream>>>(qws, kful, vt, o_msk, ah);
  gemm128<1><<<256, 256, 0, stream>>>(ah, wm_t, 32, nullptr, nullptr, nullptr,
                                      nullptr, x, xa);
  ln_k<<<4096, 256, 0, stream>>>(xa, g2, b2, xn);
  gemm128<1><<<256, 256, 0, stream>>>(xn, wl_t, 32, nullptr, nullptr, nullptr,
                                      nullptr, xa, o_xm);
}

// Round 2
// 449.119 us; speedup vs baseline: 1.5203x; 1.5203x over previous
//
#include <hip/hip_runtime.h>
#include <hip/hip_bf16.h>

typedef _Float16 half8 __attribute__((ext_vector_type(8)));
typedef _Float16 half4v __attribute__((ext_vector_type(4)));
typedef float f32x4 __attribute__((ext_vector_type(4)));

#define DEV static __device__ __forceinline__

// Problem constants: B=4, T=1024, D=1024, H=16, HD=64, TP=1024, SKV=2048

typedef __attribute__((address_space(1))) const unsigned int* gas_p;
typedef __attribute__((address_space(3))) unsigned int* las_p;
DEV void glds16(const void* g, void* s) {
  __builtin_amdgcn_global_load_lds((gas_p)g, (las_p)s, 16, 0, 0);
}

// ---------------------------------------------------------------------------
// Weight prep: w = tanh(wt)*sigmoid(mt), stored TRANSPOSED (N x K=1024) as f16
__global__ __launch_bounds__(256) void prep_w(const float* __restrict__ wt,
                                              const float* __restrict__ mt,
                                              _Float16* __restrict__ out, int N) {
  __shared__ float tile[64][65];
  const int ntiles = N >> 6;
  const int nt = blockIdx.x % ntiles, kt = blockIdx.x / ntiles;
  const int k0 = kt << 6, n0 = nt << 6;
  const int t = threadIdx.x, r = t >> 2, c0 = (t & 3) << 4;
  const long ibase = (long)(k0 + r) * N + n0 + c0;
#pragma unroll
  for (int j = 0; j < 16; j += 4) {
    float4 a = *(const float4*)(wt + ibase + j);
    float4 b = *(const float4*)(mt + ibase + j);
    tile[r][c0 + j + 0] = tanhf(a.x) / (1.f + __expf(-b.x));
    tile[r][c0 + j + 1] = tanhf(a.y) / (1.f + __expf(-b.y));
    tile[r][c0 + j + 2] = tanhf(a.z) / (1.f + __expf(-b.z));
    tile[r][c0 + j + 3] = tanhf(a.w) / (1.f + __expf(-b.w));
  }
  __syncthreads();
  half8 o0, o1;
#pragma unroll
  for (int j = 0; j < 8; ++j) {
    o0[j] = (_Float16)tile[c0 + j][r];
    o1[j] = (_Float16)tile[c0 + 8 + j][r];
  }
  _Float16* dst = out + (long)(n0 + r) * 1024 + k0 + c0;
  *(half8*)dst = o0;
  *(half8*)(dst + 8) = o1;
}

// ---------------------------------------------------------------------------
// past[:,0] (k) fp32 -> k_full rows 0..1023 f16.
__global__ __launch_bounds__(256) void conv_pastk(const float* __restrict__ past,
                                                  _Float16* __restrict__ kf) {
  const long e = ((long)blockIdx.x * 256 + threadIdx.x) * 4;
  const int b = (int)(e >> 20);
  const int rem = (int)(e & 1048575);
  float4 v = *(const float4*)(past + (long)b * 2097152 + rem);
  half4v o = {(_Float16)v.x, (_Float16)v.y, (_Float16)v.z, (_Float16)v.w};
  const int h = rem >> 16, td = rem & 65535;
  *(half4v*)(kf + (long)(b * 16 + h) * 131072 + td) = o;
}

// ---------------------------------------------------------------------------
// LayerNorm row kernel: fp32 in -> f16 out.
__global__ __launch_bounds__(256) void ln_k(const float* __restrict__ x,
                                            const float* __restrict__ g,
                                            const float* __restrict__ be,
                                            _Float16* __restrict__ out) {
  __shared__ float red[4];
  const int row = blockIdx.x, tid = threadIdx.x, l = tid & 63, w = tid >> 6;
  float4 v = *(const float4*)(x + (long)row * 1024 + tid * 4);
  float s = v.x + v.y + v.z + v.w;
#pragma unroll
  for (int o = 32; o > 0; o >>= 1) s += __shfl_down(s, o, 64);
  if (l == 0) red[w] = s;
  __syncthreads();
  const float mu = (red[0] + red[1] + red[2] + red[3]) * (1.f / 1024.f);
  float dx = v.x - mu, dy = v.y - mu, dz = v.z - mu, dw = v.w - mu;
  float ss = dx * dx + dy * dy + dz * dz + dw * dw;
#pragma unroll
  for (int o = 32; o > 0; o >>= 1) ss += __shfl_down(ss, o, 64);
  __syncthreads();
  if (l == 0) red[w] = ss;
  __syncthreads();
  const float var = (red[0] + red[1] + red[2] + red[3]) * (1.f / 1024.f);
  const float rs = rsqrtf(var + 1e-3f);
  float4 gv = *(const float4*)(g + tid * 4);
  float4 bv = *(const float4*)(be + tid * 4);
  half4v o = {(_Float16)(dx * rs * gv.x + bv.x), (_Float16)(dy * rs * gv.y + bv.y),
              (_Float16)(dz * rs * gv.z + bv.z), (_Float16)(dw * rs * gv.w + bv.w)};
  *(half4v*)(out + (long)row * 1024 + tid * 4) = o;
}

// ---------------------------------------------------------------------------
// GEMM BMx128 tile, BK=64, 256 threads (4 waves 2x2), K=1024, glds staging,
// double-buffered LDS, 1 barrier per K-step.
template <int BM, int EPI>
__global__ __launch_bounds__(256) void gemm_k(const _Float16* __restrict__ A,
                                              const _Float16* __restrict__ Bt,
                                              int mtiles,
                                              _Float16* __restrict__ e_q,
                                              _Float16* __restrict__ e_k,
                                              _Float16* __restrict__ e_v,
                                              float* __restrict__ e_present,
                                              const float* __restrict__ e_res,
                                              float* __restrict__ e_out) {
  constexpr int FM = BM / 32;  // acc rows per wave /16; also A glds call count
  __shared__ __align__(16) char smem[2 * BM * 128 + 32768];
  char* Bbase = smem + 2 * BM * 128;
  const int tid = threadIdx.x, l = tid & 63, w = tid >> 6;
  const int wm = w >> 1, wn = w & 1;
  const int bm = blockIdx.x % mtiles, bn = blockIdx.x / mtiles;
  const long m0 = (long)bm * BM, n0 = (long)bn * 128;

  f32x4 acc[FM][4];
#pragma unroll
  for (int i = 0; i < FM; ++i)
#pragma unroll
    for (int j = 0; j < 4; ++j) acc[i][j] = (f32x4){0.f, 0.f, 0.f, 0.f};

  auto stage = [&](int b, int kt) {
#pragma unroll
    for (int i = 0; i < FM; ++i) {
      const int cid = i * 256 + tid, row = cid >> 3, u = cid & 7;
      glds16(A + (m0 + row) * 1024 + kt * 64 + ((u ^ (row & 7)) << 3),
             smem + b * BM * 128 + i * 4096 + w * 1024);
    }
#pragma unroll
    for (int i = 0; i < 4; ++i) {
      const int cid = i * 256 + tid, row = cid >> 3, u = cid & 7;
      glds16(Bt + (n0 + row) * 1024 + kt * 64 + ((u ^ (row & 7)) << 3),
             Bbase + b * 16384 + i * 4096 + w * 1024);
    }
  };

  stage(0, 0);
  __syncthreads();
  for (int kt = 0; kt < 16; ++kt) {
    const int cur = kt & 1;
    if (kt < 15) stage(cur ^ 1, kt + 1);
    const char* As = smem + cur * BM * 128;
    const char* Bs = Bbase + cur * 16384;
#pragma unroll
    for (int k2 = 0; k2 < 2; ++k2) {
      const int sl = k2 * 4 + (l >> 4);
      half8 bfr[4];
#pragma unroll
      for (int fn = 0; fn < 4; ++fn) {
        const int rn = wn * 64 + fn * 16 + (l & 15);
        bfr[fn] = *(const half8*)(Bs + rn * 128 + ((sl ^ (rn & 7)) << 4));
      }
#pragma unroll
      for (int fm = 0; fm < FM; ++fm) {
        const int rm = wm * (BM / 2) + fm * 16 + (l & 15);
        const half8 afr = *(const half8*)(As + rm * 128 + ((sl ^ (rm & 7)) << 4));
#pragma unroll
        for (int fn = 0; fn < 4; ++fn)
          acc[fm][fn] = __builtin_amdgcn_mfma_f32_16x16x32_f16(afr, bfr[fn], acc[fm][fn], 0, 0, 0);
      }
    }
    __syncthreads();
  }
#pragma unroll
  for (int fm = 0; fm < FM; ++fm) {
#pragma unroll
    for (int fn = 0; fn < 4; ++fn) {
#pragma unroll
      for (int r = 0; r < 4; ++r) {
        const long row = m0 + wm * (BM / 2) + fm * 16 + (l >> 4) * 4 + r;
        const long col = n0 + fn * 16 + (l & 15) + wn * 64;
        const float v = acc[fm][fn][r];
        if constexpr (EPI == 0) {
          const int b = (int)(row >> 10), t = (int)(row & 1023);
          const int sec = (int)(col >> 10), h = ((int)col >> 6) & 15, hd = (int)col & 63;
          const long bh = b * 16 + h;
          if (sec == 0) {
            e_q[(bh * 1024 + t) * 64 + hd] = (_Float16)v;
          } else if (sec == 1) {
            e_present[(((long)(b * 2) * 16 + h) * 1024 + t) * 64 + hd] = v;
            e_k[(bh * 2048 + 1024 + t) * 64 + hd] = (_Float16)v;
          } else {
            e_present[(((long)(b * 2 + 1) * 16 + h) * 1024 + t) * 64 + hd] = v;
            e_v[(bh * 1024 + t) * 64 + hd] = (_Float16)v;
          }
        } else {
          e_out[row * 1024 + col] = e_res[row * 1024 + col] + v;
        }
      }
    }
  }
}

// ---------------------------------------------------------------------------
// Build v^T (B,H,64,2048) f16 from past v (fp32) + new v (f16).
__global__ __launch_bounds__(256) void vt_transpose(const float* __restrict__ past,
                                                    const _Float16* __restrict__ vnew,
                                                    _Float16* __restrict__ vt) {
  __shared__ float tile[64][65];
  const int bh = blockIdx.x >> 5, kt = blockIdx.x & 31;
  const int b = bh >> 4, h = bh & 15;
  const int k0 = kt << 6;
  const int t = threadIdx.x, r = t >> 2, c0 = (t & 3) << 4;
  if (k0 < 1024) {
    const float* src = past + (((long)(b * 2 + 1) * 16 + h) * 1024 + (k0 + r)) * 64 + c0;
#pragma unroll
    for (int j = 0; j < 16; j += 4) {
      float4 v = *(const float4*)(src + j);
      tile[r][c0 + j + 0] = v.x;
      tile[r][c0 + j + 1] = v.y;
      tile[r][c0 + j + 2] = v.z;
      tile[r][c0 + j + 3] = v.w;
    }
  } else {
    const _Float16* src = vnew + ((long)bh * 1024 + (k0 - 1024 + r)) * 64 + c0;
    half8 a = *(const half8*)src;
    half8 bq = *(const half8*)(src + 8);
#pragma unroll
    for (int j = 0; j < 8; ++j) {
      tile[r][c0 + j] = (float)a[j];
      tile[r][c0 + 8 + j] = (float)bq[j];
    }
  }
  __syncthreads();
  half8 o0, o1;
#pragma unroll
  for (int j = 0; j < 8; ++j) {
    o0[j] = (_Float16)tile[c0 + j][r];
    o1[j] = (_Float16)tile[c0 + 8 + j][r];
  }
  _Float16* dst = vt + ((long)bh * 64 + r) * 2048 + k0 + c0;
  *(half8*)dst = o0;
  *(half8*)(dst + 8) = o1;
}

// ---------------------------------------------------------------------------
// Fused attention. One block per (b,h,q-tile-of-64). 256 threads, 4 blocks/CU.
// LDS: qs 8K | ks 16K (K chunk, aliased V^T chunk) | ps 16K (P f16; stats alias)
DEV void s_qk(const char* qs, const char* ks, int l, int wm, int wn,
              f32x4 (&sa)[2][4]) {
#pragma unroll
  for (int i = 0; i < 2; ++i)
#pragma unroll
    for (int j = 0; j < 4; ++j) sa[i][j] = (f32x4){0.f, 0.f, 0.f, 0.f};
#pragma unroll
  for (int k2 = 0; k2 < 2; ++k2) {
    const int sl = k2 * 4 + (l >> 4);
    half8 bfr[4];
#pragma unroll
    for (int fn = 0; fn < 4; ++fn) {
      const int rn = wn * 64 + fn * 16 + (l & 15);
      bfr[fn] = *(const half8*)(ks + rn * 128 + ((sl ^ (rn & 7)) << 4));
    }
#pragma unroll
    for (int fm = 0; fm < 2; ++fm) {
      const int rm = wm * 32 + fm * 16 + (l & 15);
      const half8 afr = *(const half8*)(qs + rm * 128 + ((sl ^ (rm & 7)) << 4));
#pragma unroll
      for (int fn = 0; fn < 4; ++fn)
        sa[fm][fn] = __builtin_amdgcn_mfma_f32_16x16x32_f16(afr, bfr[fn], sa[fm][fn], 0, 0, 0);
    }
  }
}

__global__ __launch_bounds__(256, 4) void attn_k(const _Float16* __restrict__ qg,
                                                 const _Float16* __restrict__ kg,
                                                 const _Float16* __restrict__ vtg,
                                                 float* __restrict__ msk,
                                                 _Float16* __restrict__ ah) {
  __shared__ __align__(16) char smem[40960];
  char* qs = smem;            // [64][128B]
  char* ks = smem + 8192;     // [128][128B] K chunk; aliased as v^T [64][256B]
  char* ps = smem + 24576;    // [64][256B] P f16
  float* mtmp = (float*)ps;         // [128] transient (phase boundary)
  float* stmp = (float*)(ps + 512); // [128]

  const int tid = threadIdx.x, l = tid & 63, w = tid >> 6;
  const int wm = w >> 1, wn = w & 1;
  const int bh = blockIdx.x & 63;
  const int qt = 15 - (blockIdx.x >> 6);  // heavy tiles first
  const int r0 = qt << 6;
  const int nc = (r0 + 1088 + 127) >> 7;  // kv chunks of 128

  const _Float16* qbase = qg + ((long)bh * 1024 + r0) * 64;
  const _Float16* kbase = kg + (long)bh * 131072;
  const _Float16* vtbase = vtg + (long)bh * 131072;
  float* mskbase = msk + ((long)bh * 1024 + r0) * 2048;

  // stage Q (64x64 f16) via glds, pre-swizzled source
#pragma unroll
  for (int i = 0; i < 2; ++i) {
    const int cid = i * 256 + tid, row = cid >> 3, u = cid & 7;
    glds16(qbase + row * 64 + ((u ^ (row & 7)) << 3), qs + i * 4096 + w * 1024);
  }

  // ---- phase 1: row max / sumexp
  float m_t[8], s_t[8];
#pragma unroll
  for (int i = 0; i < 8; ++i) {
    m_t[i] = -1e30f;
    s_t[i] = 0.f;
  }
  for (int c = 0; c < nc; ++c) {
    if (c) __syncthreads();
#pragma unroll
    for (int i = 0; i < 4; ++i) {
      const int cid = i * 256 + tid, row = cid >> 3, u = cid & 7;
      glds16(kbase + (long)(c * 128 + row) * 64 + ((u ^ (row & 7)) << 3),
             ks + i * 4096 + w * 1024);
    }
    __syncthreads();
    f32x4 sa[2][4];
    s_qk(qs, ks, l, wm, wn, sa);
#pragma unroll
    for (int fm = 0; fm < 2; ++fm) {
#pragma unroll
      for (int r = 0; r < 4; ++r) {
        const int row_l = wm * 32 + fm * 16 + (l >> 4) * 4 + r;
        const int lim = r0 + row_l + 1024;
        float vv[4];
#pragma unroll
        for (int fn = 0; fn < 4; ++fn) {
          const int col = c * 128 + wn * 64 + fn * 16 + (l & 15);
          vv[fn] = (col <= lim) ? sa[fm][fn][r] * 0.125f : -1e30f;
        }
        const float cm = fmaxf(fmaxf(vv[0], vv[1]), fmaxf(vv[2], vv[3]));
        const int ix = fm * 4 + r;
        const float mo = m_t[ix];
        const float mn = fmaxf(mo, cm);
        s_t[ix] = s_t[ix] * __expf(mo - mn) + __expf(vv[0] - mn) + __expf(vv[1] - mn) +
                  __expf(vv[2] - mn) + __expf(vv[3] - mn);
        m_t[ix] = mn;
      }
    }
  }
  // cross-lane reduce within wave (16 lanes share a row)
#pragma unroll
  for (int ix = 0; ix < 8; ++ix) {
    float m = m_t[ix], s = s_t[ix];
#pragma unroll
    for (int mk = 1; mk <= 8; mk <<= 1) {
      const float om = __shfl_xor(m, mk, 64);
      const float os = __shfl_xor(s, mk, 64);
      const float mn = fmaxf(m, om);
      s = s * __expf(m - mn) + os * __expf(om - mn);
      m = mn;
    }
    m_t[ix] = m;
    s_t[ix] = s;
  }
  if ((l & 15) == 0) {
#pragma unroll
    for (int fm = 0; fm < 2; ++fm)
#pragma unroll
      for (int r = 0; r < 4; ++r) {
        const int row_l = wm * 32 + fm * 16 + (l >> 4) * 4 + r;
        mtmp[wn * 64 + row_l] = m_t[fm * 4 + r];
        stmp[wn * 64 + row_l] = s_t[fm * 4 + r];
      }
  }
  __syncthreads();
  float li_t[8];
#pragma unroll
  for (int fm = 0; fm < 2; ++fm)
#pragma unroll
    for (int r = 0; r < 4; ++r) {
      const int row_l = wm * 32 + fm * 16 + (l >> 4) * 4 + r;
      const float ma = mtmp[row_l], mb = mtmp[64 + row_l];
      const float sva = stmp[row_l], svb = stmp[64 + row_l];
      const float mf = fmaxf(ma, mb);
      const int ix = fm * 4 + r;
      m_t[ix] = mf;
      li_t[ix] = 1.f / (sva * __expf(ma - mf) + svb * __expf(mb - mf));
    }

  // ---- phase 2: P, msk, PV
  f32x4 pv[4];
#pragma unroll
  for (int j = 0; j < 4; ++j) pv[j] = (f32x4){0.f, 0.f, 0.f, 0.f};
  for (int c = 0; c < nc; ++c) {
    __syncthreads();  // prev PV v^T reads done / mtmp reads done
#pragma unroll
    for (int i = 0; i < 4; ++i) {
      const int cid = i * 256 + tid, row = cid >> 3, u = cid & 7;
      glds16(kbase + (long)(c * 128 + row) * 64 + ((u ^ (row & 7)) << 3),
             ks + i * 4096 + w * 1024);
    }
    __syncthreads();  // K chunk ready
    f32x4 sa[2][4];
    s_qk(qs, ks, l, wm, wn, sa);
#pragma unroll
    for (int fm = 0; fm < 2; ++fm) {
#pragma unroll
      for (int r = 0; r < 4; ++r) {
        const int row_l = wm * 32 + fm * 16 + (l >> 4) * 4 + r;
        const int ix = fm * 4 + r;
        const int lim = r0 + row_l + 1024;
        const float mref = m_t[ix], linv = li_t[ix];
#pragma unroll
        for (int fn = 0; fn < 4; ++fn) {
          const int col_l = wn * 64 + fn * 16 + (l & 15);
          const int col = c * 128 + col_l;
          const float p = (col <= lim) ? __expf(sa[fm][fn][r] * 0.125f - mref) * linv : 0.f;
          *(_Float16*)(ps + row_l * 256 + ((((col_l >> 3) & 15) ^ (row_l & 7)) << 4) +
                       ((col_l & 7) << 1)) = (_Float16)p;
        }
      }
    }
    __syncthreads();  // ks reads done, ps complete
#pragma unroll
    for (int i = 0; i < 4; ++i) {  // stage v^T chunk into ks region
      const int cid = i * 256 + tid, row = cid >> 4, u = cid & 15;
      glds16(vtbase + (long)row * 2048 + c * 128 + ((u ^ (row & 7)) << 3),
             ks + i * 4096 + w * 1024);
    }
    // coalesced msk store from ps (overlaps v^T load latency)
#pragma unroll
    for (int j = 0; j < 8; ++j) {
      const int sid = j * 256 + tid, row = sid >> 5, slot = sid & 31;
      const int unit = (slot >> 1) ^ (row & 7);
      half4v h = *(const half4v*)(ps + row * 256 + (unit << 4) + ((slot & 1) << 3));
      float4 o = make_float4((float)h[0], (float)h[1], (float)h[2], (float)h[3]);
      *(float4*)(mskbase + (long)row * 2048 + c * 128 + slot * 4) = o;
    }
    __syncthreads();  // v^T ready
#pragma unroll
    for (int k2 = 0; k2 < 4; ++k2) {
      const int sl = k2 * 4 + (l >> 4);
      half8 bv[4];
#pragma unroll
      for (int fn2 = 0; fn2 < 4; ++fn2) {
        const int rd = fn2 * 16 + (l & 15);
        bv[fn2] = *(const half8*)(ks + rd * 256 + ((sl ^ (rd & 7)) << 4));
      }
      const int rp = w * 16 + (l & 15);
      const half8 ap = *(const half8*)(ps + rp * 256 + ((sl ^ (rp & 7)) << 4));
#pragma unroll
      for (int fn2 = 0; fn2 < 4; ++fn2)
        pv[fn2] = __builtin_amdgcn_mfma_f32_16x16x32_f16(ap, bv[fn2], pv[fn2], 0, 0, 0);
    }
  }
  // zero-fill fully-masked tail columns
  const int tailf4 = (16 - nc) << 5;
  if (tailf4 > 0 && tid < tailf4) {
    const float4 z4 = make_float4(0.f, 0.f, 0.f, 0.f);
    for (int row = 0; row < 64; ++row)
      *(float4*)(mskbase + (long)row * 2048 + nc * 128 + tid * 4) = z4;
  }
  // attention output rows -> ah (B*T,1024) f16
  const int b_ = bh >> 4, h_ = bh & 15;
#pragma unroll
  for (int fn2 = 0; fn2 < 4; ++fn2)
#pragma unroll
    for (int rr = 0; rr < 4; ++rr) {
      const int row_l = w * 16 + (l >> 4) * 4 + rr;
      const long bt = (long)b_ * 1024 + r0 + row_l;
      ah[bt * 1024 + h_ * 64 + fn2 * 16 + (l & 15)] = (_Float16)pv[fn2][rr];
    }
}

// ---------------------------------------------------------------------------
extern "C" void kernel_launch(void* const* d_in, const int* in_sizes, int n_in,
                              void* d_out, int out_size, void* d_ws, size_t ws_size,
                              hipStream_t stream) {
  const float* x = (const float*)d_in[0];
  const float* past = (const float*)d_in[1];
  const float* qkv_wt = (const float*)d_in[2];
  const float* qkv_mt = (const float*)d_in[3];
  const float* merge_wt = (const float*)d_in[4];
  const float* merge_mt = (const float*)d_in[5];
  const float* ln1_wt = (const float*)d_in[6];
  const float* ln1_mt = (const float*)d_in[7];
  const float* g1 = (const float*)d_in[8];
  const float* b1 = (const float*)d_in[9];
  const float* g2 = (const float*)d_in[10];
  const float* b2 = (const float*)d_in[11];

  float* out = (float*)d_out;
  float* o_xm = out;                       // (4,1024,1024)
  float* o_present = out + 4194304;        // (4,2,16,1024,64)
  float* o_msk = out + 4194304 + 8388608;  // (4,16,1024,2048)

  char* ws = (char*)d_ws;
  _Float16* wq_t = (_Float16*)(ws + 0);         // 3072x1024 f16
  _Float16* wm_t = (_Float16*)(ws + 6291456);   // 1024x1024 f16
  _Float16* wl_t = (_Float16*)(ws + 8388608);   // 1024x1024 f16
  _Float16* xn   = (_Float16*)(ws + 10485760);  // 4096x1024 f16
  _Float16* qws  = (_Float16*)(ws + 18874368);  // (4,16,1024,64)
  _Float16* kful = (_Float16*)(ws + 27262976);  // (4,16,2048,64)
  _Float16* vnew = (_Float16*)(ws + 44040192);  // (4,16,1024,64)
  _Float16* vt   = (_Float16*)(ws + 52428800);  // (4,16,64,2048)
  _Float16* ah   = (_Float16*)(ws + 69206016);  // 4096x1024 f16
  float* xa      = (float*)(ws + 77594624);     // 4096x1024 f32

  prep_w<<<768, 256, 0, stream>>>(qkv_wt, qkv_mt, wq_t, 3072);
  prep_w<<<256, 256, 0, stream>>>(merge_wt, merge_mt, wm_t, 1024);
  prep_w<<<256, 256, 0, stream>>>(ln1_wt, ln1_mt, wl_t, 1024);
  conv_pastk<<<4096, 256, 0, stream>>>(past, kful);
  ln_k<<<4096, 256, 0, stream>>>(x, g1, b1, xn);
  gemm_k<128, 0><<<768, 256, 0, stream>>>(xn, wq_t, 32, qws, kful, vnew, o_present,
                                          nullptr, nullptr);
  vt_transpose<<<2048, 256, 0, stream>>>(past, vnew, vt);
  attn_k<<<1024, 256, 0, stream>>>(qws, kful, vt, o_msk, ah);
  gemm_k<64, 1><<<512, 256, 0, stream>>>(ah, wm_t, 64, nullptr, nullptr, nullptr,
                                         nullptr, x, xa);
  ln_k<<<4096, 256, 0, stream>>>(xa, g2, b2, xn);
  gemm_k<64, 1><<<512, 256, 0, stream>>>(xn, wl_t, 64, nullptr, nullptr, nullptr,
                                         nullptr, xa, o_xm);
}